// Round 4
// baseline (641.296 us; speedup 1.0000x reference)
//
#include <hip/hip_runtime.h>

typedef short short8 __attribute__((ext_vector_type(8)));
typedef float floatx4 __attribute__((ext_vector_type(4)));

#define LEAKY(v) ((v) >= 0.0f ? (v) : 0.01f * (v))

constexpr int D = 256;  // in = hid = out = 256

__device__ __forceinline__ short f2bf(float x) {
  unsigned u = __float_as_uint(x);
  u += 0x7fffu + ((u >> 16) & 1u);  // RNE (finite inputs)
  return (short)(u >> 16);
}
__device__ __forceinline__ float bf2f(short s) {
  return __uint_as_float(((unsigned)(unsigned short)s) << 16);
}

// ---- W transpose+convert: Wt[n][k] = bf16(Wsrc[k][n]), 3 matrices ----------
__global__ void transpose_w(const float* __restrict__ W1,
                            const float* __restrict__ W2,
                            const float* __restrict__ Wl,
                            short* __restrict__ Wt) {
  __shared__ float t[32][33];
  const float* src = (blockIdx.z == 0) ? W1 : (blockIdx.z == 1) ? W2 : Wl;
  short* dst = Wt + (size_t)blockIdx.z * D * D;
  int tx = threadIdx.x, ty = threadIdx.y;
  t[ty][tx] = src[(size_t)(blockIdx.y * 32 + ty) * D + blockIdx.x * 32 + tx];
  __syncthreads();
  dst[(size_t)(blockIdx.x * 32 + ty) * D + blockIdx.y * 32 + tx] =
      f2bf(t[tx][ty]);
}

// ---- strip MFMA GEMM: C[M,256] = A[M,256] @ Wt^T (+epilogue) ---------------
// Zero LDS, zero barriers. 512 thr = 8 waves; per strip (16 rows), wave w
// owns cols w*32..w*32+31 (2 n-frags). B frags (64 VGPR) loaded ONCE and
// PINNED via asm volatile so the compiler cannot rematerialize them as
// per-MFMA global loads (the r1-r3 failure: VGPR_Count 56-88 proved B was
// being re-loaded from memory inside the loop). A frags pinned likewise.
// Blocks grid-stride over strips; all 8 waves of a block read the same A
// rows -> L1 absorbs the redundancy. ~130 VGPR -> 3 waves/SIMD.
template <bool A_F32, bool ADD_ROW, bool FINAL>
__global__ __launch_bounds__(512, 2) void gemm_strip(
    const void* __restrict__ Avoid, const short* __restrict__ Wt,
    const float* __restrict__ R, const int* __restrict__ batch,
    const float* __restrict__ bias, void* __restrict__ Cvoid, int M,
    int nStrips) {
  const int tid = threadIdx.x;
  const int l = tid & 63, w = tid >> 6, lm = l & 15, q = l >> 4;
  const int ncol0 = w * 32;

  // resident B fragments: 2 n-frags x 8 k-frags, 16B/lane each -> 64 VGPR
  short8 bf[2][8];
#pragma unroll
  for (int j = 0; j < 2; j++)
#pragma unroll
    for (int kk = 0; kk < 8; kk++) {
      bf[j][kk] = *(const short8*)(Wt + (size_t)(ncol0 + j * 16 + lm) * D +
                                   kk * 32 + q * 8);
      asm volatile("" : "+v"(bf[j][kk]));  // pin: no remat, no re-load
    }

  float4 b4[2];
  if (FINAL) {
#pragma unroll
    for (int j = 0; j < 2; j++)
      b4[j] = *(const float4*)(bias + ncol0 + j * 16 + q * 4);
  }

  for (int sp = blockIdx.x; sp < nStrips; sp += gridDim.x) {
    const int row = sp * 16 + lm;          // this lane's A row
    const int rl = row < M ? row : M - 1;  // clamp (stores guarded)

    short8 a[8];  // lane holds A[row][kk*32 + q*8 .. +7], kk = 0..7
    if (A_F32) {
      const float* ap = (const float*)Avoid + (size_t)rl * D + q * 8;
#pragma unroll
      for (int kk = 0; kk < 8; kk++) {
        float4 v0 = *(const float4*)(ap + (size_t)kk * 32);
        float4 v1 = *(const float4*)(ap + (size_t)kk * 32 + 4);
        short8 sv;
        sv[0] = f2bf(v0.x); sv[1] = f2bf(v0.y); sv[2] = f2bf(v0.z); sv[3] = f2bf(v0.w);
        sv[4] = f2bf(v1.x); sv[5] = f2bf(v1.y); sv[6] = f2bf(v1.z); sv[7] = f2bf(v1.w);
        a[kk] = sv;
        asm volatile("" : "+v"(a[kk]));
      }
    } else {
      const short* ap = (const short*)Avoid + (size_t)rl * D + q * 8;
#pragma unroll
      for (int kk = 0; kk < 8; kk++) {
        a[kk] = *(const short8*)(ap + (size_t)kk * 32);
        asm volatile("" : "+v"(a[kk]));
      }
    }

    floatx4 acc[2];
    acc[0] = (floatx4){0.f, 0.f, 0.f, 0.f};
    acc[1] = (floatx4){0.f, 0.f, 0.f, 0.f};
#pragma unroll
    for (int kk = 0; kk < 8; kk++)
#pragma unroll
      for (int j = 0; j < 2; j++)
        acc[j] = __builtin_amdgcn_mfma_f32_16x16x32_bf16(bf[j][kk], a[kk],
                                                         acc[j], 0, 0, 0);

    // lane holds: row = sp*16+lm, cols ncol0 + j*16 + q*4 .. +3
    if (row < M) {
      int rb = 0;
      if (ADD_ROW) rb = batch[row];
#pragma unroll
      for (int j = 0; j < 2; j++) {
        const int col0 = ncol0 + j * 16 + q * 4;
        float c0 = acc[j][0], c1 = acc[j][1], c2 = acc[j][2], c3 = acc[j][3];
        if (ADD_ROW) {
          float4 rv = *(const float4*)(R + (size_t)rb * D + col0);
          c0 += rv.x; c1 += rv.y; c2 += rv.z; c3 += rv.w;
        }
        if (!FINAL) {
          uint2 o;
          o.x = (unsigned)(unsigned short)f2bf(c0) |
                ((unsigned)(unsigned short)f2bf(c1) << 16);
          o.y = (unsigned)(unsigned short)f2bf(c2) |
                ((unsigned)(unsigned short)f2bf(c3) << 16);
          *(uint2*)((short*)Cvoid + (size_t)row * D + col0) = o;
        } else {
          c0 += b4[j].x; c1 += b4[j].y; c2 += b4[j].z; c3 += b4[j].w;
          c0 = LEAKY(c0); c1 = LEAKY(c1); c2 = LEAKY(c2); c3 = LEAKY(c3);
          float4 o = {c0, c1, c2, c3};
          *(float4*)((float*)Cvoid + (size_t)row * D + col0) = o;
        }
      }
    }
  }
}

// ---------------- CSR build --------------------------------------------------
__global__ void count_dst(const int* __restrict__ dst, int* __restrict__ offs,
                          int E) {
  int e = blockIdx.x * 256 + threadIdx.x;
  if (e < E) atomicAdd(&offs[dst[e]], 1);
}

__global__ void scan_blocks(int* __restrict__ offs, int* __restrict__ bsums,
                            int n) {
  __shared__ int tmp[256];
  int i = blockIdx.x * 256 + threadIdx.x;
  int v = (i < n) ? offs[i] : 0;
  tmp[threadIdx.x] = v;
  __syncthreads();
  for (int off = 1; off < 256; off <<= 1) {
    int t = (threadIdx.x >= off) ? tmp[threadIdx.x - off] : 0;
    __syncthreads();
    tmp[threadIdx.x] += t;
    __syncthreads();
  }
  if (i < n) offs[i] = tmp[threadIdx.x] - v;
  if (threadIdx.x == 255) bsums[blockIdx.x] = tmp[255];
}

__global__ void scan_sums(int* __restrict__ bs, int nb) {
  __shared__ int tmp[1024];
  int v = (threadIdx.x < nb) ? bs[threadIdx.x] : 0;
  tmp[threadIdx.x] = v;
  __syncthreads();
  for (int off = 1; off < 1024; off <<= 1) {
    int t = (threadIdx.x >= off) ? tmp[threadIdx.x - off] : 0;
    __syncthreads();
    tmp[threadIdx.x] += t;
    __syncthreads();
  }
  if (threadIdx.x < nb) bs[threadIdx.x] = tmp[threadIdx.x] - v;
}

__global__ void add_offsets(int* __restrict__ offs, const int* __restrict__ bs,
                            int n, int* __restrict__ cursor) {
  int i = blockIdx.x * 256 + threadIdx.x;
  if (i < n) {
    int o = offs[i] + bs[blockIdx.x];
    offs[i] = o;
    cursor[i] = o;
  }
}

__global__ void fill_buckets(const int* __restrict__ src,
                             const int* __restrict__ dst,
                             const float* __restrict__ vals,
                             int* __restrict__ cursor, int* __restrict__ esrc,
                             float* __restrict__ ew, int E) {
  int e = blockIdx.x * 256 + threadIdx.x;
  if (e < E) {
    int p = atomicAdd(&cursor[dst[e]], 1);
    esrc[p] = src[e];
    ew[p] = vals[e];
  }
}

// ---- gather agg (bf16 in/out): out[n] = bf16(leaky(sum w*H[src] + bias)) ---
__global__ __launch_bounds__(256) void aggregate_bf(
    const short* __restrict__ H, const int* __restrict__ offs,
    const int* __restrict__ esrc, const float* __restrict__ ew,
    const float* __restrict__ bias, short* __restrict__ out, int N, int E) {
  int node = blockIdx.x * 4 + (threadIdx.x >> 6);
  if (node >= N) return;
  int lane = threadIdx.x & 63;
  int beg = offs[node];
  int end = (node == N - 1) ? E : offs[node + 1];
  float a0 = 0.f, a1 = 0.f, a2 = 0.f, a3 = 0.f;
  for (int i = beg; i < end; i++) {
    int s = esrc[i];
    float wv = ew[i];
    uint2 pk = ((const uint2*)(H + (size_t)s * D))[lane];
    a0 += wv * bf2f((short)(pk.x & 0xffff));
    a1 += wv * bf2f((short)(pk.x >> 16));
    a2 += wv * bf2f((short)(pk.y & 0xffff));
    a3 += wv * bf2f((short)(pk.y >> 16));
  }
  float4 b = ((const float4*)bias)[lane];
  a0 = LEAKY(a0 + b.x);
  a1 = LEAKY(a1 + b.y);
  a2 = LEAKY(a2 + b.z);
  a3 = LEAKY(a3 + b.w);
  uint2 o;
  o.x = (unsigned)(unsigned short)f2bf(a0) |
        ((unsigned)(unsigned short)f2bf(a1) << 16);
  o.y = (unsigned)(unsigned short)f2bf(a2) |
        ((unsigned)(unsigned short)f2bf(a3) << 16);
  ((uint2*)(out + (size_t)node * D))[lane] = o;
}

// ---- R1[b,:] = leaky(features[root_b]) @ W2[256:512] (fp32) ----------------
__global__ void root_gemm1(const float* __restrict__ X,
                           const int* __restrict__ root_idx,
                           const float* __restrict__ W2,
                           float* __restrict__ R1) {
  __shared__ float a[D];
  int b = blockIdx.x, j = threadIdx.x;
  int r = root_idx[b];
  a[j] = LEAKY(X[(size_t)r * D + j]);
  __syncthreads();
  float acc = 0.f;
#pragma unroll 8
  for (int k = 0; k < D; k++) acc += a[k] * W2[(size_t)(D + k) * D + j];
  R1[b * D + j] = acc;
}

// ---- R2[b,:] = (agg1[root_b]+b1) @ Wl[256:512]  (recompute agg for root) ---
__global__ void root_gemm2(const short* __restrict__ H,
                           const int* __restrict__ root_idx,
                           const int* __restrict__ offs,
                           const int* __restrict__ esrc,
                           const float* __restrict__ ew,
                           const float* __restrict__ b1,
                           const float* __restrict__ Wl, float* __restrict__ R2,
                           int N, int E) {
  __shared__ float a[D];
  int b = blockIdx.x, j = threadIdx.x;
  int r = root_idx[b];
  int beg = offs[r], end = (r == N - 1) ? E : offs[r + 1];
  float acc = b1[j];
  for (int e = beg; e < end; e++)
    acc += ew[e] * bf2f(H[(size_t)esrc[e] * D + j]);
  a[j] = acc;
  __syncthreads();
  float s = 0.f;
#pragma unroll 8
  for (int k = 0; k < D; k++) s += a[k] * Wl[(size_t)(D + k) * D + j];
  R2[b * D + j] = s;
}

extern "C" void kernel_launch(void* const* d_in, const int* in_sizes, int n_in,
                              void* d_out, int out_size, void* d_ws,
                              size_t ws_size, hipStream_t stream) {
  const float* features = (const float*)d_in[0];  // [N,256]
  const float* values   = (const float*)d_in[1];  // [E]
  const float* W1 = (const float*)d_in[2];        // [256,256]
  const float* b1 = (const float*)d_in[3];        // [256]
  const float* W2 = (const float*)d_in[4];        // [512,256]
  const float* b2 = (const float*)d_in[5];        // [256]
  const float* Wl = (const float*)d_in[6];        // [512,256]
  const float* bl = (const float*)d_in[7];        // [256]
  const int* adjs = (const int*)d_in[8];          // [2,E]
  const int* batch = (const int*)d_in[9];         // [N]
  const int* root_idx = (const int*)d_in[10];     // [B]

  const int N = in_sizes[0] / D;
  const int E = in_sizes[1];
  const int B = in_sizes[10];
  const int* srcI = adjs;
  const int* dstI = adjs + E;

  // workspace layout
  short* bf0 = (short*)d_ws;            // h0_bf, then h2_bf   [N*256]
  short* bf1 = bf0 + (size_t)N * D;     // a1_bf, then a2_bf   [N*256]
  short* Wt = bf1 + (size_t)N * D;      // 3 x [256,256] bf16 (n-major)
  float* R1 = (float*)(Wt + (size_t)3 * D * D);  // [B,256]
  float* R2 = R1 + (size_t)B * D;                // [B,256]
  float* ew = R2 + (size_t)B * D;                // [E]
  int* offs = (int*)(ew + E);                    // [N]
  int* cursor = offs + N;                        // [N]
  int* esrc = cursor + N;                        // [E]
  int* bsums = esrc + E;                         // [<=1024]

  const int nb = (N + 255) / 256;  // 391 <= 1024

  // ---- build dst-CSR (reused by both aggregations + root2) ----
  hipMemsetAsync(offs, 0, (size_t)N * sizeof(int), stream);
  count_dst<<<(E + 255) / 256, 256, 0, stream>>>(dstI, offs, E);
  scan_blocks<<<nb, 256, 0, stream>>>(offs, bsums, N);
  scan_sums<<<1, 1024, 0, stream>>>(bsums, nb);
  add_offsets<<<nb, 256, 0, stream>>>(offs, bsums, N, cursor);
  fill_buckets<<<(E + 255) / 256, 256, 0, stream>>>(srcI, dstI, values, cursor,
                                                    esrc, ew, E);

  // ---- weights -> bf16, transposed to [n][k] ----
  transpose_w<<<dim3(8, 8, 3), dim3(32, 32), 0, stream>>>(W1, W2, Wl, Wt);

  const int nStrips = (N + 15) / 16;       // 6250
  const int sgrid = (nStrips + 3) / 4;     // ~4 strips per block
  const int aggGrid = (N + 3) / 4;

  // 1) h0 = features @ W1           (fp32 in, bf16 out)
  gemm_strip<true, false, false><<<sgrid, 512, 0, stream>>>(
      features, Wt, nullptr, nullptr, nullptr, bf0, N, nStrips);

  // 2) a1 = leaky(segsum(w*h0) + b1)  (bf16)
  aggregate_bf<<<aggGrid, 256, 0, stream>>>(bf0, offs, esrc, ew, b1, bf1, N, E);

  // 3) R1, R2 (root2 recomputes pre-leaky agg1 rows from CSR)
  root_gemm1<<<B, 256, 0, stream>>>(features, root_idx, W2, R1);
  root_gemm2<<<B, 256, 0, stream>>>(bf0, root_idx, offs, esrc, ew, b1, Wl, R2,
                                    N, E);

  // 4) h2 = a1 @ W2_top + R1[batch]   (bf16 in/out; overwrites h0 after root2)
  gemm_strip<false, true, false><<<sgrid, 512, 0, stream>>>(
      bf1, Wt + (size_t)D * D, R1, batch, nullptr, bf0, N, nStrips);

  // 5) a2 = leaky(segsum(w*h2) + b2)  (bf16)
  aggregate_bf<<<aggGrid, 256, 0, stream>>>(bf0, offs, esrc, ew, b2, bf1, N, E);

  // 6) out = leaky(a2 @ Wl_top + R2[batch] + bl)  (fp32 out)
  gemm_strip<false, true, true><<<sgrid, 512, 0, stream>>>(
      bf1, Wt + (size_t)2 * D * D, R2, batch, bl, (float*)d_out, N, nStrips);
}

// Round 5
// 479.815 us; speedup vs baseline: 1.3365x; 1.3365x over previous
//
#include <hip/hip_runtime.h>

typedef short short8 __attribute__((ext_vector_type(8)));
typedef float floatx4 __attribute__((ext_vector_type(4)));

#define LEAKY(v) ((v) >= 0.0f ? (v) : 0.01f * (v))

constexpr int D = 256;  // in = hid = out = 256

__device__ __forceinline__ short f2bf(float x) {
  unsigned u = __float_as_uint(x);
  u += 0x7fffu + ((u >> 16) & 1u);  // RNE (finite inputs)
  return (short)(u >> 16);
}
__device__ __forceinline__ float bf2f(short s) {
  return __uint_as_float(((unsigned)(unsigned short)s) << 16);
}

#define AS1 __attribute__((address_space(1)))
#define AS3 __attribute__((address_space(3)))

__device__ __forceinline__ void gload_lds16(const void* g, void* lds) {
  __builtin_amdgcn_global_load_lds((const AS1 void*)g, (AS3 void*)lds, 16, 0, 0);
}

// ---- W transpose+convert: Wt[n][k] = bf16(Wsrc[k][n]), 3 matrices ----------
__global__ void transpose_w(const float* __restrict__ W1,
                            const float* __restrict__ W2,
                            const float* __restrict__ Wl,
                            short* __restrict__ Wt) {
  __shared__ float t[32][33];
  const float* src = (blockIdx.z == 0) ? W1 : (blockIdx.z == 1) ? W2 : Wl;
  short* dst = Wt + (size_t)blockIdx.z * D * D;
  int tx = threadIdx.x, ty = threadIdx.y;
  t[ty][tx] = src[(size_t)(blockIdx.y * 32 + ty) * D + blockIdx.x * 32 + tx];
  __syncthreads();
  dst[(size_t)(blockIdx.x * 32 + ty) * D + blockIdx.y * 32 + tx] =
      f2bf(t[tx][ty]);
}

// ---- f32 -> bf16 convert (vectorized, grid-stride) -------------------------
__global__ __launch_bounds__(256) void conv_bf(const float* __restrict__ X,
                                               short* __restrict__ Y,
                                               long n8) {
  long i = (long)blockIdx.x * 256 + threadIdx.x;  // unit: 8 elements
  const long stride = (long)gridDim.x * 256;
  for (; i < n8; i += stride) {
    float4 v0 = ((const float4*)X)[2 * i];
    float4 v1 = ((const float4*)X)[2 * i + 1];
    short8 s;
    s[0] = f2bf(v0.x); s[1] = f2bf(v0.y); s[2] = f2bf(v0.z); s[3] = f2bf(v0.w);
    s[4] = f2bf(v1.x); s[5] = f2bf(v1.y); s[6] = f2bf(v1.z); s[7] = f2bf(v1.w);
    ((short8*)Y)[i] = s;
  }
}

// ---- persistent double-buffered MFMA GEMM: C[M,256]=A[M,256]@Wt^T ----------
// Grid = 256 (1 block/CU), 512 thr = 8 waves; wave w owns cols w*32..+31.
// B frags: 16 loads issued together, THEN 16 volatile pins (progressive
// waitcnt, one latency) -> truly resident in regs (remat impossible past a
// volatile asm; r1/r3 VGPR=56-64 proved the compiler otherwise re-loads B
// per MFMA; r4 proved per-load volatile pins serialize loads).
// A staged in FRAGMENT ORDER (r3, validated: 0 bank conflicts): slot
// s=kk*4+i holds the 1KB consumed as a[i] at k-block kk; global_load_lds
// writes wave-uniform dst + lane*16; reads are lane-linear ds_read_b128.
// Loop: __syncthreads(); stage(next -> buf^1); compute(t, buf) -- next
// tile's DMA is in flight across the entire compute+epilogue phase; the
// sync's vmcnt(0) drain IS the stage-completion wait (no counted-vmcnt
// store-pollution trap).
template <bool ADD_ROW, bool FINAL>
__global__ __launch_bounds__(512, 2) void gemm_pipe(
    const short* __restrict__ A, const short* __restrict__ Wt,
    const float* __restrict__ R, const int* __restrict__ batch,
    const float* __restrict__ bias, void* __restrict__ Cvoid, int M,
    int nTiles) {
  __shared__ __align__(16) short As[2][64 * 256];  // 2 x 32 KB
  const int tid = threadIdx.x;
  const int l = tid & 63, w = tid >> 6, lm = l & 15, q = l >> 4;
  const int ncol0 = w * 32;

  // resident B fragments: 2 n-frags x 8 k-frags -> 64 VGPR
  short8 bf[2][8];
#pragma unroll
  for (int j = 0; j < 2; j++)
#pragma unroll
    for (int kk = 0; kk < 8; kk++)
      bf[j][kk] = *(const short8*)(Wt + (size_t)(ncol0 + j * 16 + lm) * D +
                                   kk * 32 + q * 8);
#pragma unroll
  for (int j = 0; j < 2; j++)
#pragma unroll
    for (int kk = 0; kk < 8; kk++)
      asm volatile("" : "+v"(bf[j][kk]));  // pin AFTER all loads issued

  float4 b4[2];
  if (FINAL) {
#pragma unroll
    for (int j = 0; j < 2; j++)
      b4[j] = *(const float4*)(bias + ncol0 + j * 16 + q * 4);
  }

  const int stride = gridDim.x;
  int t = blockIdx.x;
  int p = 0;

  auto stage = [&](int tile, int buf) {
#pragma unroll
    for (int r = 0; r < 4; r++) {
      const int s = r * 8 + w;           // slot, wave-uniform
      const int kk = s >> 2, i = s & 3;  // fragment (kk, i)
      int grow = tile * 64 + i * 16 + lm;
      grow = grow < M ? grow : M - 1;  // clamp tail (stores guarded)
      const char* src = (const char*)A + (size_t)grow * 512 + kk * 64 + q * 16;
      gload_lds16(src, (char*)(&As[buf][0]) + s * 1024);
    }
  };

  if (t < nTiles) stage(t, 0);

  for (; t < nTiles; t += stride) {
    __syncthreads();  // drains vmcnt: stage(t) landed; buf p^1 released
    const int nxt = t + stride;
    if (nxt < nTiles) stage(nxt, p ^ 1);  // DMA overlaps compute below

    floatx4 acc[4][2];
#pragma unroll
    for (int i = 0; i < 4; i++)
#pragma unroll
      for (int j = 0; j < 2; j++) acc[i][j] = (floatx4){0.f, 0.f, 0.f, 0.f};

    const char* base = (const char*)(&As[p][0]) + (size_t)l * 16;
#pragma unroll
    for (int kk = 0; kk < 8; kk++) {
      short8 a[4];
#pragma unroll
      for (int i = 0; i < 4; i++)
        a[i] = *(const short8*)(base + (kk * 4 + i) * 1024);
#pragma unroll
      for (int i = 0; i < 4; i++)
#pragma unroll
        for (int j = 0; j < 2; j++)
          acc[i][j] = __builtin_amdgcn_mfma_f32_16x16x32_bf16(
              bf[j][kk], a[i], acc[i][j], 0, 0, 0);
    }

    // epilogue: lane holds rows i*16+lm, cols ncol0+j*16+q*4 .. +3
    const int rowBase = t * 64;
#pragma unroll
    for (int i = 0; i < 4; i++) {
      const int row = rowBase + i * 16 + lm;
      if (row < M) {
        int rb = 0;
        if (ADD_ROW) rb = batch[row];
#pragma unroll
        for (int j = 0; j < 2; j++) {
          const int col0 = ncol0 + j * 16 + q * 4;
          float c0 = acc[i][j][0], c1 = acc[i][j][1], c2 = acc[i][j][2],
                c3 = acc[i][j][3];
          if (ADD_ROW) {
            float4 rv = *(const float4*)(R + (size_t)rb * D + col0);
            c0 += rv.x; c1 += rv.y; c2 += rv.z; c3 += rv.w;
          }
          if (!FINAL) {
            uint2 o;
            o.x = (unsigned)(unsigned short)f2bf(c0) |
                  ((unsigned)(unsigned short)f2bf(c1) << 16);
            o.y = (unsigned)(unsigned short)f2bf(c2) |
                  ((unsigned)(unsigned short)f2bf(c3) << 16);
            *(uint2*)((short*)Cvoid + (size_t)row * D + col0) = o;
          } else {
            c0 += b4[j].x; c1 += b4[j].y; c2 += b4[j].z; c3 += b4[j].w;
            c0 = LEAKY(c0); c1 = LEAKY(c1); c2 = LEAKY(c2); c3 = LEAKY(c3);
            float4 o = {c0, c1, c2, c3};
            *(float4*)((float*)Cvoid + (size_t)row * D + col0) = o;
          }
        }
      }
    }
    p ^= 1;
  }
}

// ---------------- CSR build --------------------------------------------------
__global__ void count_dst(const int* __restrict__ dst, int* __restrict__ offs,
                          int E) {
  int e = blockIdx.x * 256 + threadIdx.x;
  if (e < E) atomicAdd(&offs[dst[e]], 1);
}

__global__ void scan_blocks(int* __restrict__ offs, int* __restrict__ bsums,
                            int n) {
  __shared__ int tmp[256];
  int i = blockIdx.x * 256 + threadIdx.x;
  int v = (i < n) ? offs[i] : 0;
  tmp[threadIdx.x] = v;
  __syncthreads();
  for (int off = 1; off < 256; off <<= 1) {
    int t = (threadIdx.x >= off) ? tmp[threadIdx.x - off] : 0;
    __syncthreads();
    tmp[threadIdx.x] += t;
    __syncthreads();
  }
  if (i < n) offs[i] = tmp[threadIdx.x] - v;
  if (threadIdx.x == 255) bsums[blockIdx.x] = tmp[255];
}

__global__ void scan_sums(int* __restrict__ bs, int nb) {
  __shared__ int tmp[1024];
  int v = (threadIdx.x < nb) ? bs[threadIdx.x] : 0;
  tmp[threadIdx.x] = v;
  __syncthreads();
  for (int off = 1; off < 1024; off <<= 1) {
    int t = (threadIdx.x >= off) ? tmp[threadIdx.x - off] : 0;
    __syncthreads();
    tmp[threadIdx.x] += t;
    __syncthreads();
  }
  if (threadIdx.x < nb) bs[threadIdx.x] = tmp[threadIdx.x] - v;
}

__global__ void add_offsets(int* __restrict__ offs, const int* __restrict__ bs,
                            int n, int* __restrict__ cursor) {
  int i = blockIdx.x * 256 + threadIdx.x;
  if (i < n) {
    int o = offs[i] + bs[blockIdx.x];
    offs[i] = o;
    cursor[i] = o;
  }
}

__global__ void fill_buckets(const int* __restrict__ src,
                             const int* __restrict__ dst,
                             const float* __restrict__ vals,
                             int* __restrict__ cursor, int* __restrict__ esrc,
                             float* __restrict__ ew, int E) {
  int e = blockIdx.x * 256 + threadIdx.x;
  if (e < E) {
    int p = atomicAdd(&cursor[dst[e]], 1);
    esrc[p] = src[e];
    ew[p] = vals[e];
  }
}

// ---- gather agg (bf16 in/out): out[n] = bf16(leaky(sum w*H[src] + bias)) ---
__global__ __launch_bounds__(256) void aggregate_bf(
    const short* __restrict__ H, const int* __restrict__ offs,
    const int* __restrict__ esrc, const float* __restrict__ ew,
    const float* __restrict__ bias, short* __restrict__ out, int N, int E) {
  int node = blockIdx.x * 4 + (threadIdx.x >> 6);
  if (node >= N) return;
  int lane = threadIdx.x & 63;
  int beg = offs[node];
  int end = (node == N - 1) ? E : offs[node + 1];
  float a0 = 0.f, a1 = 0.f, a2 = 0.f, a3 = 0.f;
  for (int i = beg; i < end; i++) {
    int s = esrc[i];
    float wv = ew[i];
    uint2 pk = ((const uint2*)(H + (size_t)s * D))[lane];
    a0 += wv * bf2f((short)(pk.x & 0xffff));
    a1 += wv * bf2f((short)(pk.x >> 16));
    a2 += wv * bf2f((short)(pk.y & 0xffff));
    a3 += wv * bf2f((short)(pk.y >> 16));
  }
  float4 b = ((const float4*)bias)[lane];
  a0 = LEAKY(a0 + b.x);
  a1 = LEAKY(a1 + b.y);
  a2 = LEAKY(a2 + b.z);
  a3 = LEAKY(a3 + b.w);
  uint2 o;
  o.x = (unsigned)(unsigned short)f2bf(a0) |
        ((unsigned)(unsigned short)f2bf(a1) << 16);
  o.y = (unsigned)(unsigned short)f2bf(a2) |
        ((unsigned)(unsigned short)f2bf(a3) << 16);
  ((uint2*)(out + (size_t)node * D))[lane] = o;
}

// ---- R1[b,:] = leaky(features[root_b]) @ W2[256:512] (fp32) ----------------
__global__ void root_gemm1(const float* __restrict__ X,
                           const int* __restrict__ root_idx,
                           const float* __restrict__ W2,
                           float* __restrict__ R1) {
  __shared__ float a[D];
  int b = blockIdx.x, j = threadIdx.x;
  int r = root_idx[b];
  a[j] = LEAKY(X[(size_t)r * D + j]);
  __syncthreads();
  float acc = 0.f;
#pragma unroll 8
  for (int k = 0; k < D; k++) acc += a[k] * W2[(size_t)(D + k) * D + j];
  R1[b * D + j] = acc;
}

// ---- R2[b,:] = (agg1[root_b]+b1) @ Wl[256:512]  (recompute agg for root) ---
__global__ void root_gemm2(const short* __restrict__ H,
                           const int* __restrict__ root_idx,
                           const int* __restrict__ offs,
                           const int* __restrict__ esrc,
                           const float* __restrict__ ew,
                           const float* __restrict__ b1,
                           const float* __restrict__ Wl, float* __restrict__ R2,
                           int N, int E) {
  __shared__ float a[D];
  int b = blockIdx.x, j = threadIdx.x;
  int r = root_idx[b];
  int beg = offs[r], end = (r == N - 1) ? E : offs[r + 1];
  float acc = b1[j];
  for (int e = beg; e < end; e++)
    acc += ew[e] * bf2f(H[(size_t)esrc[e] * D + j]);
  a[j] = acc;
  __syncthreads();
  float s = 0.f;
#pragma unroll 8
  for (int k = 0; k < D; k++) s += a[k] * Wl[(size_t)(D + k) * D + j];
  R2[b * D + j] = s;
}

extern "C" void kernel_launch(void* const* d_in, const int* in_sizes, int n_in,
                              void* d_out, int out_size, void* d_ws,
                              size_t ws_size, hipStream_t stream) {
  const float* features = (const float*)d_in[0];  // [N,256]
  const float* values   = (const float*)d_in[1];  // [E]
  const float* W1 = (const float*)d_in[2];        // [256,256]
  const float* b1 = (const float*)d_in[3];        // [256]
  const float* W2 = (const float*)d_in[4];        // [512,256]
  const float* b2 = (const float*)d_in[5];        // [256]
  const float* Wl = (const float*)d_in[6];        // [512,256]
  const float* bl = (const float*)d_in[7];        // [256]
  const int* adjs = (const int*)d_in[8];          // [2,E]
  const int* batch = (const int*)d_in[9];         // [N]
  const int* root_idx = (const int*)d_in[10];     // [B]

  const int N = in_sizes[0] / D;
  const int E = in_sizes[1];
  const int B = in_sizes[10];
  const int* srcI = adjs;
  const int* dstI = adjs + E;

  // workspace layout
  short* bf0 = (short*)d_ws;            // h0_bf, then h2_bf   [N*256]
  short* bf1 = bf0 + (size_t)N * D;     // feat_bf, a1_bf, a2_bf [N*256]
  short* Wt = bf1 + (size_t)N * D;      // 3 x [256,256] bf16 (n-major)
  float* R1 = (float*)(Wt + (size_t)3 * D * D);  // [B,256]
  float* R2 = R1 + (size_t)B * D;                // [B,256]
  float* ew = R2 + (size_t)B * D;                // [E]
  int* offs = (int*)(ew + E);                    // [N]
  int* cursor = offs + N;                        // [N]
  int* esrc = cursor + N;                        // [E]
  int* bsums = esrc + E;                         // [<=1024]

  const int nb = (N + 255) / 256;  // 391 <= 1024

  // ---- build dst-CSR (reused by both aggregations + root2) ----
  hipMemsetAsync(offs, 0, (size_t)N * sizeof(int), stream);
  count_dst<<<(E + 255) / 256, 256, 0, stream>>>(dstI, offs, E);
  scan_blocks<<<nb, 256, 0, stream>>>(offs, bsums, N);
  scan_sums<<<1, 1024, 0, stream>>>(bsums, nb);
  add_offsets<<<nb, 256, 0, stream>>>(offs, bsums, N, cursor);
  fill_buckets<<<(E + 255) / 256, 256, 0, stream>>>(srcI, dstI, values, cursor,
                                                    esrc, ew, E);

  // ---- weights -> bf16, transposed to [n][k] ----
  transpose_w<<<dim3(8, 8, 3), dim3(32, 32), 0, stream>>>(W1, W2, Wl, Wt);

  // ---- features -> bf16 (into bf1; consumed by gemm1 before step 2) ----
  conv_bf<<<2048, 256, 0, stream>>>(features, bf1, (long)N * D / 8);

  const int nTiles = (N + 63) / 64;  // 1563
  const int ggrid = 256;             // persistent, 1 block/CU
  const int aggGrid = (N + 3) / 4;

  // 1) h0 = features @ W1           (bf16 in, bf16 out)
  gemm_pipe<false, false><<<ggrid, 512, 0, stream>>>(
      bf1, Wt, nullptr, nullptr, nullptr, bf0, N, nTiles);

  // 2) a1 = leaky(segsum(w*h0) + b1)  (bf16; overwrites feat_bf)
  aggregate_bf<<<aggGrid, 256, 0, stream>>>(bf0, offs, esrc, ew, b1, bf1, N, E);

  // 3) R1, R2 (root2 recomputes pre-leaky agg1 rows from CSR)
  root_gemm1<<<B, 256, 0, stream>>>(features, root_idx, W2, R1);
  root_gemm2<<<B, 256, 0, stream>>>(bf0, root_idx, offs, esrc, ew, b1, Wl, R2,
                                    N, E);

  // 4) h2 = a1 @ W2_top + R1[batch]   (bf16 in/out; overwrites h0 after root2)
  gemm_pipe<true, false><<<ggrid, 512, 0, stream>>>(
      bf1, Wt + (size_t)D * D, R1, batch, nullptr, bf0, N, nTiles);

  // 5) a2 = leaky(segsum(w*h2) + b2)  (bf16)
  aggregate_bf<<<aggGrid, 256, 0, stream>>>(bf0, offs, esrc, ew, b2, bf1, N, E);

  // 6) out = leaky(a2 @ Wl_top + R2[batch] + bl)  (fp32 out)
  gemm_pipe<true, true><<<ggrid, 512, 0, stream>>>(
      bf1, Wt + (size_t)2 * D * D, R2, batch, bl, (float*)d_out, N, nTiles);
}